// Round 3
// baseline (427.197 us; speedup 1.0000x reference)
//
#include <hip/hip_runtime.h>
#include <hip/hip_bf16.h>
#include <float.h>
#include <math.h>

#define N_TOK 16384
#define DIM   2048
#define NE    64
#define KH    1024       // K per split half
#define KT    32         // K tile per staging step
#define NKT   32         // KH/KT
#define KTP   36         // padded LDS leading dim
#define EPSF  1e-9f

// ---------- wave-wide helpers (wave64) ----------
__device__ __forceinline__ float wave_sum(float v) {
#pragma unroll
    for (int d = 32; d > 0; d >>= 1) v += __shfl_xor(v, d, 64);
    return v;
}

// max with lowest-index tie-break (matches jax.lax.top_k ordering)
__device__ __forceinline__ void wave_argmax(float v, int i, float& mv, int& mi) {
    float bv = v; int bi = i;
#pragma unroll
    for (int d = 32; d > 0; d >>= 1) {
        float ov = __shfl_xor(bv, d, 64);
        int   oi = __shfl_xor(bi, d, 64);
        if (ov > bv || (ov == bv && oi < bi)) { bv = ov; bi = oi; }
    }
    mv = bv; mi = bi;
}

// ---------- GEMM: 64 tok x 64 rows x K=1024 per block, partials to P[ks] ----------
// grid = 1024 blocks = 256 token-tiles x {gate,noise} x {K-half}; 128 thr (2 waves)
__global__ __launch_bounds__(128, 2) void gemm64_kernel(
    const float* __restrict__ x,   // [N_TOK][DIM]
    const float* __restrict__ Wg,  // [NE][DIM]
    const float* __restrict__ Wn,  // [NE][DIM]
    float* __restrict__ P)         // [2][N_TOK][128] partial logits
{
    __shared__ float xs[64][KTP];
    __shared__ float wsh[64][KTP];

    // XCD-aware swizzle (nwg=1024, bijective): the 4 blocks sharing an x-tile
    // land on the same XCD -> x 2nd read hits that XCD's L2.
    const int wg   = blockIdx.x;
    const int L    = (wg & 7) * 128 + (wg >> 3);
    const int tt   = L >> 2;
    const int half = (L >> 1) & 1;
    const int ks   = L & 1;

    const int t    = threadIdx.x;
    const int f4c  = t & 7;        // staging: float4 column 0..7
    const int rowb = t >> 3;       // staging: row seed 0..15
    const int tg   = t >> 3;       // compute: token group 0..15 -> tokens tg+16i
    const int og   = t & 7;        // compute: row group   0..7  -> rows   og+8j

    const float* W = half ? Wn : Wg;
    const int tokBase = tt * 64;
    const int kbase   = ks * KH;

    float acc[4][8];
#pragma unroll
    for (int i = 0; i < 4; ++i)
#pragma unroll
        for (int j = 0; j < 8; ++j) acc[i][j] = 0.f;

    // register prefetch of tile kt=0
    float4 px[4], pw[4];
#pragma unroll
    for (int r = 0; r < 4; ++r) {
        px[r] = *(const float4*)(x + (size_t)(tokBase + rowb + 16 * r) * DIM + kbase + f4c * 4);
        pw[r] = *(const float4*)(W + (size_t)(rowb + 16 * r) * DIM + kbase + f4c * 4);
    }

    for (int kt = 0; kt < NKT; ++kt) {
        __syncthreads();            // previous compute done reading LDS
#pragma unroll
        for (int r = 0; r < 4; ++r) {
            *(float4*)&xs[rowb + 16 * r][f4c * 4]  = px[r];
            *(float4*)&wsh[rowb + 16 * r][f4c * 4] = pw[r];
        }
        __syncthreads();
        if (kt < NKT - 1) {
            const int koff = kbase + (kt + 1) * KT;
#pragma unroll
            for (int r = 0; r < 4; ++r) {
                px[r] = *(const float4*)(x + (size_t)(tokBase + rowb + 16 * r) * DIM + koff + f4c * 4);
                pw[r] = *(const float4*)(W + (size_t)(rowb + 16 * r) * DIM + koff + f4c * 4);
            }
        }
#pragma unroll
        for (int kk4 = 0; kk4 < KT / 4; ++kk4) {
            float4 xv[4], wv[8];
#pragma unroll
            for (int i = 0; i < 4; ++i)
                xv[i] = *(const float4*)&xs[tg + 16 * i][kk4 * 4];
#pragma unroll
            for (int j = 0; j < 8; ++j)
                wv[j] = *(const float4*)&wsh[og + 8 * j][kk4 * 4];
#pragma unroll
            for (int i = 0; i < 4; ++i)
#pragma unroll
                for (int j = 0; j < 8; ++j) {
                    acc[i][j] += xv[i].x * wv[j].x;
                    acc[i][j] += xv[i].y * wv[j].y;
                    acc[i][j] += xv[i].z * wv[j].z;
                    acc[i][j] += xv[i].w * wv[j].w;
                }
        }
    }

    float* Pk = P + (size_t)ks * N_TOK * 128;
#pragma unroll
    for (int i = 0; i < 4; ++i)
#pragma unroll
        for (int j = 0; j < 8; ++j)
            Pk[(size_t)(tokBase + tg + 16 * i) * 128 + half * 64 + og + 8 * j] = acc[i][j];
}

// ---------- epilogue: sum K-halves + router math, 32 tokens/block ----------
__global__ __launch_bounds__(256) void epilogue_kernel(
    const float* __restrict__ P,      // [2][N_TOK][128]
    const float* __restrict__ noise,  // [N_TOK][NE]
    float* __restrict__ out,          // topi(2N) | weights(2N) | priority(N) | aux(1)
    float* __restrict__ accum)        // importance[64] | load[64]
{
    __shared__ float s_part[4][2][NE];
    const int t    = threadIdx.x;
    const int wv   = t >> 6;   // 0..3
    const int lane = t & 63;   // expert id
    const float* P0 = P;
    const float* P1 = P + (size_t)N_TOK * 128;

    float imp_acc = 0.f, load_acc = 0.f;

    for (int s = 0; s < 8; ++s) {
        const int tok = blockIdx.x * 32 + wv * 8 + s;

        float logit = P0[(size_t)tok * 128 + lane]      + P1[(size_t)tok * 128 + lane];
        float rawn  = P0[(size_t)tok * 128 + 64 + lane] + P1[(size_t)tok * 128 + 64 + lane];
        // softplus (stable, matches jax.nn.softplus) + EPS
        float sp   = fmaxf(rawn, 0.f) + log1pf(expf(-fabsf(rawn)));
        float nstd = sp + EPSF;
        float nz   = noise[(size_t)tok * NE + lane];
        float noisy = logit + nz * nstd;

        // top-3 of 64 lanes
        float v0, v1, v2; int i0, i1, i2d;
        wave_argmax(noisy, lane, v0, i0);
        float m1 = (lane == i0) ? -FLT_MAX : noisy;
        wave_argmax(m1, lane, v1, i1);
        float m2 = (lane == i0 || lane == i1) ? -FLT_MAX : noisy;
        wave_argmax(m2, lane, v2, i2d);
        (void)i2d;

        // softmax over the two surviving entries (max = v0)
        float e1  = expf(v1 - v0);
        float den = 1.f + e1;
        float w0v = 1.f / den;
        float w1v = e1 / den;

        if (lane == 0) {
            out[2 * tok]                 = (float)i0;   // topi
            out[2 * tok + 1]             = (float)i1;
            out[2 * N_TOK + 2 * tok]     = w0v;         // weights
            out[2 * N_TOK + 2 * tok + 1] = w1v;
            out[4 * N_TOK + tok]         = w0v;         // priority = max weight
        }

        // importance contribution (gates_full row is zero except top-2)
        imp_acc += (lane == i0) ? w0v : ((lane == i1) ? w1v : 0.f);

        // load contribution: Phi((logits - kth_excl)/(noise_std+EPS))
        bool in_topk = (lane == i0) || (lane == i1);
        float kth = in_topk ? v2 : v1;
        float z = (logit - kth) / (nstd + EPSF);
        load_acc += 0.5f * (1.f + erff(z * 0.7071067811865476f));
    }

    s_part[wv][0][lane] = imp_acc;
    s_part[wv][1][lane] = load_acc;
    __syncthreads();

    if (t < 2 * NE) {
        int which = t >> 6, e = t & 63;
        float s = s_part[0][which][e] + s_part[1][which][e]
                + s_part[2][which][e] + s_part[3][which][e];
        atomicAdd(&accum[which * NE + e], s);
    }
}

// ---------- finalize: aux = 0.1*cv2(importance) + 0.1*cv2(load) ----------
__global__ void finalize_kernel(const float* __restrict__ accum,
                                float* __restrict__ out_aux) {
    const int lane = threadIdx.x;  // 64 threads
    float imp  = accum[lane];
    float load = accum[NE + lane];

    float m_imp = wave_sum(imp) * (1.f / NE);
    float di = imp - m_imp;
    float var_imp = wave_sum(di * di) * (1.f / NE);

    float m_load = wave_sum(load) * (1.f / NE);
    float dl = load - m_load;
    float var_load = wave_sum(dl * dl) * (1.f / NE);

    if (lane == 0) {
        out_aux[0] = 0.1f * (var_imp  / (m_imp  * m_imp  + EPSF))
                   + 0.1f * (var_load / (m_load * m_load + EPSF));
    }
}

extern "C" void kernel_launch(void* const* d_in, const int* in_sizes, int n_in,
                              void* d_out, int out_size, void* d_ws, size_t ws_size,
                              hipStream_t stream) {
    const float* x     = (const float*)d_in[0];
    const float* noise = (const float*)d_in[1];
    const float* Wg    = (const float*)d_in[2];
    const float* Wn    = (const float*)d_in[3];
    float* out   = (float*)d_out;
    float* accum = (float*)d_ws;                 // [128]
    float* P     = accum + 128;                  // [2][N_TOK][128] = 16.8 MB

    hipMemsetAsync(accum, 0, 2 * NE * sizeof(float), stream);
    gemm64_kernel<<<1024, 128, 0, stream>>>(x, Wg, Wn, P);
    epilogue_kernel<<<N_TOK / 32, 256, 0, stream>>>(P, noise, out, accum);
    finalize_kernel<<<1, 64, 0, stream>>>(accum, out + 5 * (size_t)N_TOK);
}